// Round 18
// baseline (1331.952 us; speedup 1.0000x reference)
//
#include <hip/hip_runtime.h>

// ModalVerlet: B=16, M=64, T=48000. 1 scan + 2 storer waves.
//
// R18: COALESCED STORER. y layout (B,2M,T) with lane=mode made every
// global_store_dwordx4 span 64 cache lines (192KB lane stride) in ALL prior
// rounds - ~2048 cyc/tile of store transactions ~ 32 cyc/step, the invariant
// residual that survived every scan-side optimization. Now storer lane
// l=(mo=l>>4, tq=l&15) stores mode 4i+mo, times 4tq..4tq+3: each instruction
// covers 4 contiguous 256B runs -> 4-8 transactions (16x fewer).
//  - LDS quad-rows padded to NM+1 so the storer's transposed reads are ~free
//    (scan's contiguous writes unaffected).
//  - p = GdiC*(z_next - z_prev) central difference: in-lane + __shfl within
//    16-lane tq-groups; tile-boundary z via per-mode lub; GdiC via LDS table.
// Scan verbatim R17 (absmax 2.0): composed 2-step map on even/odd chains,
// quad-rate trans refresh, z-only quad stores.

#define NB 16
#define NM 64
#define NT 48000
#define SPI 64
#define NITER (NT / SPI) // 750

__global__ void __launch_bounds__(192, 1) modal_scan_kernel(
    const float* __restrict__ y0,
    const float* __restrict__ omega,
    const float* __restrict__ sigma,
    const float* __restrict__ gamma,
    const float* __restrict__ Phi_e,
    const float* __restrict__ fe_points,
    float* __restrict__ y_out)
{
    const int b   = blockIdx.x;
    const int wid = threadIdx.x >> 6;
    const int m   = threadIdx.x & 63;

    __shared__ float4 lz[2][SPI / 4][NM + 1]; // z quads, padded rows; ~33KB
    __shared__ float2 lub[2][NM];             // (z_{start-1}, z_{end}) per mode
    __shared__ float  lgdic[NM];              // per-mode Gd/CAGB

    const float k    = 1.0f / 48000.0f;
    const float k2   = 0.5f * k;
    const float invC = 0.34657359027997264f; // ln(2)/2
    const float Cc   = 2.885390081777927f;   // 2*log2(e)

    if (wid == 0) {
        // ---------------- scan wave (R17 verbatim; LDS stride NM+1) --------
        const float om  = omega[b * NM + m];
        const float sg  = sigma[b * NM + m];
        const float g   = gamma[b];
        const float phe = Phi_e[b * NM + m];
        const float om2 = om * om;
        const float g2  = g * g;

        const float E    = 1.0f - k * sg;
        const float dinv = 1.0f / (1.0f + k * sg);
        const float A    = k * E;
        const float Bc   = k * k2;
        const float Fd   = E * dinv;
        const float Gd   = k2 * dinv;
        const float AGB  = A * Gd + Bc;
        const float m2g2 = -2.0f * g2;

        const float CAGB = Cc * AGB;
        const float mom2C = -om2 * invC;
        const float GdF1 = Gd * (1.0f + Fd);
        const float CAu  = (Cc * A) * GdF1;

        // composed-map coefficients
        const float aM = fmaf(CAGB, mom2C, 1.0f);
        const float bM = CAu;
        const float cM = mom2C;
        const float dM = Fd;
        const float bc = bM * cM;
        const float A2 = fmaf(aM, aM, bc);
        const float B2 = bM * (aM + dM);
        const float C2 = cM * (aM + dM);
        const float D2 = fmaf(dM, dM, bc);
        const float E1 = fmaf(aM, CAGB, bM);
        const float F1 = fmaf(cM, CAGB, dM);

        const float q0v = y0[b * 2 * NM + m];
        const float p0v = y0[b * 2 * NM + NM + m];

        const float4* fe4 = reinterpret_cast<const float4*>(fe_points + (size_t)b * NT);

        float4 bufA[8], bufB[8];
#pragma unroll
        for (int i = 0; i < 8; ++i) bufA[i] = fe4[i];      // fe[0..31]
#pragma unroll
        for (int i = 0; i < 8; ++i) bufB[i] = fe4[8 + i];  // fe[32..63]

        // ---- preamble: states 0 (even) and 1 (odd) + trans priming ----
        float ze = Cc * q0v;
        float eP = __builtin_amdgcn_exp2f(ze);
        float rC = __builtin_amdgcn_rcpf(eP + 1.0f);
        float hbase = fmaf(m2g2, rC, g2);
        float ue, zo, uo, zm1, zql = 0.0f;
        {
            float h00 = fmaf(phe, bufA[0].x, hbase);
            float kl0 = fmaf(mom2C, ze, h00);
            ue = fmaf(-Gd, kl0, p0v) / GdF1;               // u_0
            zo = fmaf(CAGB, kl0, fmaf(CAu, ue, ze));       // z_1
            uo = fmaf(Fd, ue, kl0);                        // u_1
            zm1 = fmaf(-CAGB, ue, ze);                     // synthetic z_{-1}
        }

#define COMP(Z, U, H0, H1) {                              \
    float t1 = CAGB * (H1);                               \
    float hz = fmaf(E1, (H0), t1);                        \
    float hu = fmaf(F1, (H0), (H1));                      \
    float zN = fmaf(A2, (Z), fmaf(B2, (U), hz));          \
    float uN = fmaf(C2, (Z), fmaf(D2, (U), hu));          \
    (Z) = zN; (U) = uN; }

#define QUAD(F, FNX, SP, TP) {                            \
    float h0 = fmaf(phe, (F).x, hbase);                   \
    float h1 = fmaf(phe, (F).y, hbase);                   \
    float h2 = fmaf(phe, (F).z, hbase);                   \
    float h3 = fmaf(phe, (F).w, hbase);                   \
    float h4 = fmaf(phe, (FNX), hbase);                   \
    float aT = eP + 1.0f;                                 \
    float za = ze, zb = zo;                               \
    COMP(ze, ue, h0, h1);                                 \
    COMP(zo, uo, h1, h2);                                 \
    float rN = __builtin_amdgcn_rcpf(aT);                 \
    float eN = __builtin_amdgcn_exp2f(ze);                \
    (SP)[(TP) * (NM + 1)] = make_float4(za, zb, ze, zo);  \
    zql = zo;                                             \
    COMP(ze, ue, h2, h3);                                 \
    COMP(zo, uo, h3, h4);                                 \
    eP = eN; rC = rN;                                     \
    hbase = fmaf(m2g2, rC, g2); }

#define QUAD8(BUF, BNX, SP, TPB) \
    QUAD(BUF[0], BUF[1].x, SP, (TPB) + 0);  QUAD(BUF[1], BUF[2].x, SP, (TPB) + 1);  \
    QUAD(BUF[2], BUF[3].x, SP, (TPB) + 2);  QUAD(BUF[3], BUF[4].x, SP, (TPB) + 3);  \
    QUAD(BUF[4], BUF[5].x, SP, (TPB) + 4);  QUAD(BUF[5], BUF[6].x, SP, (TPB) + 5);  \
    QUAD(BUF[6], BUF[7].x, SP, (TPB) + 6);  QUAD(BUF[7], (BNX),    SP, (TPB) + 7);

#define TILE(JT, SP) {                                            \
    const int jn = ((JT) + 1 < NITER) ? ((JT) + 1) : (JT);        \
    QUAD8(bufA, bufB[0].x, SP, 0);                                \
    _Pragma("unroll")                                             \
    for (int i = 0; i < 8; ++i) bufA[i] = fe4[16 * jn + i];       \
    QUAD8(bufB, bufA[0].x, SP, 8);                                \
    _Pragma("unroll")                                             \
    for (int i = 0; i < 8; ++i) bufB[i] = fe4[16 * jn + 8 + i];   \
    lub[(JT) & 1][m] = make_float2(zm1, ze);                      \
    zm1 = zql;                                                    \
    __syncthreads(); }

        float4* sp0 = &lz[0][0][m];
        float4* sp1 = &lz[1][0][m];
        for (int j = 0; j < NITER; j += 2) {
            TILE(j, sp0);
            TILE(j + 1, sp1);
        }
#undef TILE
#undef QUAD8
#undef QUAD
#undef COMP
    } else {
        // ---------------- storer waves (wpar = 0,1), transposed lanes ------
        const int wpar = wid - 1;
        const int tq = m & 15;    // time-quad within tile: times 4tq..4tq+3
        const int mo = m >> 4;    // mode offset 0..3 (mode = 4i + mo)

        // per-mode GdiC table (both storer waves write identical values)
        {
            const float sg   = sigma[b * NM + m];
            const float E    = 1.0f - k * sg;
            const float dinv = 1.0f / (1.0f + k * sg);
            const float A    = k * E;
            const float Gd   = k2 * dinv;
            const float AGB  = A * Gd + k * k2;
            lgdic[m] = Gd / (Cc * AGB);   // p_s = GdiC*(z_{s+1}-z_{s-1})
        }

        float* yb = y_out + (size_t)b * 2 * NM * NT;

        for (int j = 0; j < NITER; ++j) {
            __syncthreads();            // publishes tile j (slot j&1) + lub
            if ((j & 1) != wpar) continue;
            const int sl = j & 1;

#pragma unroll
            for (int i = 0; i < 16; ++i) {
                const int mm = 4 * i + mo;
                float4 zq = lz[sl][tq][mm];
                float gdic = lgdic[mm];
                float2 bz = lub[sl][mm];
                // neighbor z across time: shuffle within 16-lane tq-groups
                float znb = __shfl_down(zq.x, 1, 16); // lane tq+1's first z
                float zpb = __shfl_up(zq.w, 1, 16);   // lane tq-1's last z
                float zprev = (tq == 0)  ? bz.x : zpb;
                float znext = (tq == 15) ? bz.y : znb;

                float4 qv = make_float4(invC * zq.x, invC * zq.y,
                                        invC * zq.z, invC * zq.w);
                float4 pv = make_float4(gdic * (zq.y - zprev),
                                        gdic * (zq.z - zq.x),
                                        gdic * (zq.w - zq.y),
                                        gdic * (znext - zq.z));

                size_t off = (size_t)mm * NT + (size_t)SPI * j + 4 * tq;
                *reinterpret_cast<float4*>(yb + off) = qv;
                *reinterpret_cast<float4*>(yb + off + (size_t)NM * NT) = pv;
            }
        }
    }
}

// w[b,t] = sum_m Phi_o[b,m] * y[b,m,t]  (fully parallel, memory/L3-bound)
__global__ void __launch_bounds__(256) w_kernel(
    const float* __restrict__ y,
    const float* __restrict__ Phi_o,
    float* __restrict__ w)
{
    const int b  = blockIdx.y;
    const int t4 = blockIdx.x * 256 + threadIdx.x;
    if (t4 >= NT / 4) return;

    const float4* yb = reinterpret_cast<const float4*>(y + (size_t)b * 2 * NM * NT);
    const float*  po = Phi_o + b * NM;

    float4 acc = make_float4(0.f, 0.f, 0.f, 0.f);
    #pragma unroll 8
    for (int mm = 0; mm < NM; ++mm) {
        float  c = po[mm];
        float4 v = yb[mm * (NT / 4) + t4];
        acc.x = fmaf(c, v.x, acc.x);
        acc.y = fmaf(c, v.y, acc.y);
        acc.z = fmaf(c, v.z, acc.z);
        acc.w = fmaf(c, v.w, acc.w);
    }
    reinterpret_cast<float4*>(w + (size_t)b * NT)[t4] = acc;
}

extern "C" void kernel_launch(void* const* d_in, const int* in_sizes, int n_in,
                              void* d_out, int out_size, void* d_ws, size_t ws_size,
                              hipStream_t stream)
{
    // inputs: 0=fs, 1=num_samples, 2=y0, 3=omega, 4=sigma, 5=gamma,
    //         6=Phi_e, 7=Phi_o, 8=fe_points
    const float* y0    = (const float*)d_in[2];
    const float* omega = (const float*)d_in[3];
    const float* sigma = (const float*)d_in[4];
    const float* gamma = (const float*)d_in[5];
    const float* Phi_e = (const float*)d_in[6];
    const float* Phi_o = (const float*)d_in[7];
    const float* fe    = (const float*)d_in[8];

    float* y_out = (float*)d_out;                    // (B, 2M, T)
    float* w_out = y_out + (size_t)NB * 2 * NM * NT; // (B, T)

    modal_scan_kernel<<<NB, 192, 0, stream>>>(y0, omega, sigma, gamma, Phi_e, fe, y_out);

    dim3 grid((NT / 4 + 255) / 256, NB);
    w_kernel<<<grid, 256, 0, stream>>>(y_out, Phi_o, w_out);
}